// Round 5
// baseline (247.917 us; speedup 1.0000x reference)
//
#include <hip/hip_runtime.h>

#define N1 2048
#define N2 32768
#define DD 1024
#define BM 128
#define BN 128
#define BK 128          // fp8 elements per K-tile = 128 B/row
#define NBN (N2 / BN)   // 256
#define NBM (N1 / BM)   // 16
#define KT  (DD / BK)   // 8

typedef __attribute__((ext_vector_type(8))) int   i32x8;
typedef __attribute__((ext_vector_type(4))) int   i32x4;
typedef __attribute__((ext_vector_type(4))) float f32x4;

typedef const __attribute__((address_space(1))) void gv_t;
typedef __attribute__((address_space(3))) void       lv_t;

__device__ __forceinline__ void gload16(const void* g, void* l) {
  __builtin_amdgcn_global_load_lds((gv_t*)g, (lv_t*)l, 16, 0, 0);
}

__device__ __forceinline__ unsigned ordf(float x) {  // order-preserving f32->u32
  union { float f; unsigned u; } a; a.f = x;
  return a.u ^ ((unsigned)((int)a.u >> 31) | 0x80000000u);
}

// Row-normalize + convert to fp8 e4m3 (x16 pre-scale; ranking is
// scale-invariant, final rescore is exact fp32).
__global__ __launch_bounds__(256) void nrmcvt8(const float* __restrict__ src,
                                               unsigned char* __restrict__ dst,
                                               float* __restrict__ invn) {
  const int row = blockIdx.x, t = threadIdx.x;
  const float4* s4 = (const float4*)(src + (size_t)row * DD);
  float4 v = s4[t];
  float ss = v.x * v.x + v.y * v.y + v.z * v.z + v.w * v.w;
  #pragma unroll
  for (int o = 32; o > 0; o >>= 1) ss += __shfl_down(ss, o, 64);
  __shared__ float red[4];
  if ((t & 63) == 0) red[t >> 6] = ss;
  __syncthreads();
  float inv = 1.0f / sqrtf(red[0] + red[1] + red[2] + red[3]);
  float sc = inv * 16.0f;
  int p = 0;
  p = __builtin_amdgcn_cvt_pk_fp8_f32(v.x * sc, v.y * sc, p, false);
  p = __builtin_amdgcn_cvt_pk_fp8_f32(v.z * sc, v.w * sc, p, true);
  ((unsigned*)(dst + (size_t)row * DD))[t] = (unsigned)p;
  if (invn != nullptr && t == 0) invn[row] = inv;
}

// MX-fp8 (unit-scale) MFMA GEMM + fused per-row/per-64col-strip top-4.
// A (query panel, L2-resident) loaded DIRECT to registers with 1-KT
// prefetch; B staged via global_load_lds (XOR-swizzled source, rule #21).
__global__ __launch_bounds__(256, 2) void gemm_topk(
    const unsigned char* __restrict__ qb,
    const unsigned char* __restrict__ mbn,
    unsigned* __restrict__ cand_k) {
  __shared__ char lds[65536];  // B dbuf 2x16KB; scores union 64KB
  const int tid  = threadIdx.x;
  const int lane = tid & 63;
  const int w = tid >> 6, wr = w >> 1, wc = w & 1;

  // XCD-aware bijective swizzle (grid 4096 % 8 == 0)
  int bid = blockIdx.x;
  int swz = (bid & 7) * (NBM * NBN / 8) + (bid >> 3);
  const int bm = swz >> 8;          // NBN == 256
  const int bn = swz & (NBN - 1);

  const char* bG = (const char*)(mbn + (size_t)bn * BN * DD);
  // A fragment base for this lane: row = bm*128 + wr*64 + (lane&15),
  // k-bytes (lane>>4)*32; per i add i*16 rows; per kt add kt*128.
  const char* aW = (const char*)(qb +
      (size_t)(bm * BM + wr * 64 + (lane & 15)) * DD) + (lane >> 4) * 32;

  f32x4 acc[4][4] = {};

  auto stageB = [&](int d, int kt) {
    #pragma unroll
    for (int it = 0; it < 4; ++it) {
      int p = it * 256 + tid;
      int r = p >> 3, c = p & 7, cs = c ^ (r & 7);
      gload16(bG + (size_t)r * DD + kt * BK + cs * 16,
              lds + d * 16384 + p * 16);
    }
  };

  i32x4 alo[4], ahi[4], nlo[4], nhi[4];
  auto loadA = [&](int kt, i32x4 (&lo)[4], i32x4 (&hi)[4]) {
    #pragma unroll
    for (int i = 0; i < 4; ++i) {
      lo[i] = *(const i32x4*)(aW + (size_t)i * 16 * DD + kt * BK);
      hi[i] = *(const i32x4*)(aW + (size_t)i * 16 * DD + kt * BK + 16);
    }
  };

  auto compute = [&](int d, const i32x4 (&lo)[4], const i32x4 (&hi)[4]) {
    const char* Bbuf = lds + d * 16384;
    const int g2 = 2 * (lane >> 4);
    i32x8 bb[4];
    #pragma unroll
    for (int i = 0; i < 4; ++i) {
      int rb = wc * 64 + i * 16 + (lane & 15);
      i32x4 blo = *(const i32x4*)(Bbuf + rb * 128 + ((g2 ^ (rb & 7)) * 16));
      i32x4 bhi = *(const i32x4*)(Bbuf + rb * 128 + (((g2 + 1) ^ (rb & 7)) * 16));
      bb[i] = __builtin_shufflevector(blo, bhi, 0, 1, 2, 3, 4, 5, 6, 7);
    }
    #pragma unroll
    for (int i = 0; i < 4; ++i) {
      i32x8 af = __builtin_shufflevector(lo[i], hi[i], 0, 1, 2, 3, 4, 5, 6, 7);
      #pragma unroll
      for (int j = 0; j < 4; ++j)
        acc[i][j] = __builtin_amdgcn_mfma_scale_f32_16x16x128_f8f6f4(
            af, bb[j], acc[i][j], 0 /*A=e4m3*/, 0 /*B=e4m3*/,
            0, 0x7F7F7F7F, 0, 0x7F7F7F7F /*unit e8m0 scales*/);
    }
  };

  // 2-phase pipeline, 2-unrolled for register ping-pong (static indexing).
  stageB(0, 0); loadA(0, alo, ahi);
  __syncthreads();
  #pragma unroll 1
  for (int t = 0; t < KT; t += 2) {
    if (t + 1 < KT) { stageB(1, t + 1); loadA(t + 1, nlo, nhi); }
    compute(0, alo, ahi);
    __syncthreads();
    if (t + 2 < KT) { stageB(0, t + 2); loadA(t + 2, alo, ahi); }
    compute(1, nlo, nhi);
    __syncthreads();
  }

  // ---- epilogue: scores -> LDS (rotated, scalar both ways), strip top-4 ----
  float* sc = (float*)lds;
  #pragma unroll
  for (int i = 0; i < 4; ++i)
    #pragma unroll
    for (int j = 0; j < 4; ++j)
      #pragma unroll
      for (int q = 0; q < 4; ++q) {
        int r = wr * 64 + i * 16 + (lane >> 4) * 4 + q;
        int c = wc * 64 + j * 16 + (lane & 15);
        sc[r * 128 + ((c + r) & 127)] = acc[i][j][q];
      }
  __syncthreads();

  // 256 threads = 128 rows x 2 strips of 64 cols. Branchless sorted-insert
  // of packed keys (17-bit ordered score | 15-bit global m-index).
  const int srow = tid >> 1, strip = tid & 1;
  unsigned k0 = 0, k1 = 0, k2 = 0, k3 = 0;
  for (int i = 0; i < 64; ++i) {
    int c = strip * 64 + i;
    float s = sc[srow * 128 + ((c + srow) & 127)];
    unsigned key = (ordf(s) & 0xFFFF8000u) | (unsigned)(bn * BN + c);
    unsigned b = key, t2;
    t2 = k0 < b ? k0 : b; k0 = k0 < b ? b : k0; b = t2;
    t2 = k1 < b ? k1 : b; k1 = k1 < b ? b : k1; b = t2;
    t2 = k2 < b ? k2 : b; k2 = k2 < b ? b : k2; b = t2;
    k3 = k3 < b ? b : k3;
  }
  unsigned* dst = cand_k + (size_t)(bm * BM + srow) * (NBN * 8) + bn * 8 + strip * 4;
  *(uint4*)dst = make_uint4(k0, k1, k2, k3);
}

// One wave per query row: top-16 of 2048 packed keys, exact fp32 rescore,
// stable top-4, gather synth rows and average.
__global__ __launch_bounds__(256) void finalize(
    const float* __restrict__ q, const float* __restrict__ m,
    const float* __restrict__ synth, const unsigned* __restrict__ cand_k,
    const float* __restrict__ inv_mn, float* __restrict__ out) {
  const int lane = threadIdx.x & 63;
  const int row  = blockIdx.x * 4 + (threadIdx.x >> 6);

  uint4 kk[8];
  const uint4* kp = (const uint4*)(cand_k + (size_t)row * (NBN * 8));
  #pragma unroll
  for (int ii = 0; ii < 8; ++ii) kk[ii] = kp[ii * 64 + lane];

  const float4* qp = (const float4*)(q + (size_t)row * DD);
  float4 qv[4];
  #pragma unroll
  for (int ph = 0; ph < 4; ++ph) qv[ph] = qp[ph * 64 + lane];

  unsigned wk[16];
  #pragma unroll
  for (int it = 0; it < 16; ++it) {
    unsigned lm = 0;
    #pragma unroll
    for (int ii = 0; ii < 8; ++ii) {
      unsigned a = kk[ii].x > kk[ii].y ? kk[ii].x : kk[ii].y;
      unsigned b = kk[ii].z > kk[ii].w ? kk[ii].z : kk[ii].w;
      a = a > b ? a : b;
      lm = lm > a ? lm : a;
    }
    #pragma unroll
    for (int o = 1; o < 64; o <<= 1) {
      unsigned other = (unsigned)__shfl_xor((int)lm, o, 64);
      lm = lm > other ? lm : other;
    }
    wk[it] = lm;
    #pragma unroll
    for (int ii = 0; ii < 8; ++ii) {
      kk[ii].x = kk[ii].x == lm ? 0u : kk[ii].x;
      kk[ii].y = kk[ii].y == lm ? 0u : kk[ii].y;
      kk[ii].z = kk[ii].z == lm ? 0u : kk[ii].z;
      kk[ii].w = kk[ii].w == lm ? 0u : kk[ii].w;
    }
  }

  float cosv[16]; int gidx[16];
  #pragma unroll
  for (int it = 0; it < 16; ++it) {
    int g = (int)(wk[it] & 0x7FFFu);
    gidx[it] = g;
    const float4* mp = (const float4*)(m + (size_t)g * DD);
    float d = 0.f;
    #pragma unroll
    for (int ph = 0; ph < 4; ++ph) {
      float4 mv = mp[ph * 64 + lane];
      d += mv.x * qv[ph].x + mv.y * qv[ph].y + mv.z * qv[ph].z + mv.w * qv[ph].w;
    }
    #pragma unroll
    for (int o = 1; o < 64; o <<= 1) d += __shfl_xor(d, o, 64);
    cosv[it] = d * inv_mn[g];
  }

  int sel[4]; bool used[16] = {};
  #pragma unroll
  for (int s = 0; s < 4; ++s) {
    float bv = -1e30f; int bg = 0x7FFFFFFF; int bj = -1;
    #pragma unroll
    for (int j = 0; j < 16; ++j) {
      bool better = !used[j] && (cosv[j] > bv || (cosv[j] == bv && gidx[j] < bg));
      bv = better ? cosv[j] : bv;
      bg = better ? gidx[j] : bg;
      bj = better ? j : bj;
    }
    sel[s] = bg;
    #pragma unroll
    for (int j = 0; j < 16; ++j) used[j] = used[j] || (j == bj);
  }

  const float4* s0 = (const float4*)(synth + (size_t)sel[0] * DD);
  const float4* s1 = (const float4*)(synth + (size_t)sel[1] * DD);
  const float4* s2 = (const float4*)(synth + (size_t)sel[2] * DD);
  const float4* s3 = (const float4*)(synth + (size_t)sel[3] * DD);
  float4* op = (float4*)(out + (size_t)row * DD);
  #pragma unroll
  for (int ph = 0; ph < 4; ++ph) {
    int ix = ph * 64 + lane;
    float4 a = s0[ix], b = s1[ix], c = s2[ix], d = s3[ix];
    float4 r;
    r.x = (a.x + b.x + c.x + d.x) * 0.25f;
    r.y = (a.y + b.y + c.y + d.y) * 0.25f;
    r.z = (a.z + b.z + c.z + d.z) * 0.25f;
    r.w = (a.w + b.w + c.w + d.w) * 0.25f;
    op[ix] = r;
  }
}

extern "C" void kernel_launch(void* const* d_in, const int* in_sizes, int n_in,
                              void* d_out, int out_size, void* d_ws, size_t ws_size,
                              hipStream_t stream) {
  (void)in_sizes; (void)n_in; (void)out_size; (void)ws_size;
  const float* q = (const float*)d_in[0];
  const float* m = (const float*)d_in[1];
  const float* s = (const float*)d_in[2];
  float* out = (float*)d_out;

  // ws layout: qb 2MB | mb 32MB (at 2MB) | inv_mn (at 40MB) | cand_k (at 41MB, 16MB)
  char* w = (char*)d_ws;
  unsigned char* qb     = (unsigned char*)w;
  unsigned char* mb     = (unsigned char*)(w + (2ull << 20));
  float*         inv_mn = (float*)(w + (40ull << 20));
  unsigned*      cand_k = (unsigned*)(w + (41ull << 20));

  nrmcvt8<<<N1, 256, 0, stream>>>(q, qb, nullptr);
  nrmcvt8<<<N2, 256, 0, stream>>>(m, mb, inv_mn);
  gemm_topk<<<NBM * NBN, 256, 0, stream>>>(qb, mb, cand_k);
  finalize<<<N1 / 4, 256, 0, stream>>>(q, m, s, cand_k, inv_mn, out);
}

// Round 7
// 230.495 us; speedup vs baseline: 1.0756x; 1.0756x over previous
//
#include <hip/hip_runtime.h>

#define N1 2048
#define N2 32768
#define DD 1024
#define BM 128
#define BN 128
#define BK 128          // fp8 elements per K-tile = 128 B/row
#define NBN (N2 / BN)   // 256
#define NBM (N1 / BM)   // 16
#define KT  (DD / BK)   // 8

typedef __attribute__((ext_vector_type(8))) int   i32x8;
typedef __attribute__((ext_vector_type(4))) int   i32x4;
typedef __attribute__((ext_vector_type(4))) float f32x4;

typedef const __attribute__((address_space(1))) void gv_t;
typedef __attribute__((address_space(3))) void       lv_t;

__device__ __forceinline__ void gload16(const void* g, void* l) {
  __builtin_amdgcn_global_load_lds((gv_t*)g, (lv_t*)l, 16, 0, 0);
}

// Pinned-issue 32B A-load: volatile asm cannot be sunk by the scheduler.
// EARLY-CLOBBER outputs ("=&v") — the first load must not be allocated on
// top of the address pair %2, which the second load still reads (R6 crash).
// The matching wait is the compiler's s_waitcnt vmcnt(0) before each
// s_barrier (forced by stageB's tracked global_load_lds; vmcnt is global).
__device__ __forceinline__ void aload32(const char* p, i32x4& lo, i32x4& hi) {
  asm volatile("global_load_dwordx4 %0, %2, off\n\t"
               "global_load_dwordx4 %1, %2, off offset:16"
               : "=&v"(lo), "=&v"(hi) : "v"(p));
}

__device__ __forceinline__ unsigned ordf(float x) {  // order-preserving f32->u32
  union { float f; unsigned u; } a; a.f = x;
  return a.u ^ ((unsigned)((int)a.u >> 31) | 0x80000000u);
}

// Row-normalize + convert to fp8 e4m3 (x16 pre-scale; ranking is
// scale-invariant, final rescore is exact fp32).
__global__ __launch_bounds__(256) void nrmcvt8(const float* __restrict__ src,
                                               unsigned char* __restrict__ dst,
                                               float* __restrict__ invn) {
  const int row = blockIdx.x, t = threadIdx.x;
  const float4* s4 = (const float4*)(src + (size_t)row * DD);
  float4 v = s4[t];
  float ss = v.x * v.x + v.y * v.y + v.z * v.z + v.w * v.w;
  #pragma unroll
  for (int o = 32; o > 0; o >>= 1) ss += __shfl_down(ss, o, 64);
  __shared__ float red[4];
  if ((t & 63) == 0) red[t >> 6] = ss;
  __syncthreads();
  float inv = 1.0f / sqrtf(red[0] + red[1] + red[2] + red[3]);
  float sc = inv * 16.0f;
  int p = 0;
  p = __builtin_amdgcn_cvt_pk_fp8_f32(v.x * sc, v.y * sc, p, false);
  p = __builtin_amdgcn_cvt_pk_fp8_f32(v.z * sc, v.w * sc, p, true);
  ((unsigned*)(dst + (size_t)row * DD))[t] = (unsigned)p;
  if (invn != nullptr && t == 0) invn[row] = inv;
}

// MX-fp8 (unit-scale) MFMA GEMM + fused per-row/per-64col-strip top-4.
// A (query panel, L2-hot: 128KB reused by 256 blocks) loaded direct to
// registers via pinned asm with 1-tile prefetch; B staged via
// global_load_lds (XOR-swizzled source, rule #21).
__global__ __launch_bounds__(256, 2) void gemm_topk(
    const unsigned char* __restrict__ qb,
    const unsigned char* __restrict__ mbn,
    unsigned* __restrict__ cand_k) {
  __shared__ char lds[65536];  // B dbuf 2x16KB; scores union 64KB
  const int tid  = threadIdx.x;
  const int lane = tid & 63;
  const int w = tid >> 6, wr = w >> 1, wc = w & 1;

  // XCD-aware bijective swizzle (grid 4096 % 8 == 0)
  int bid = blockIdx.x;
  int swz = (bid & 7) * (NBM * NBN / 8) + (bid >> 3);
  const int bm = swz >> 8;          // NBN == 256
  const int bn = swz & (NBN - 1);

  const char* bG = (const char*)(mbn + (size_t)bn * BN * DD);
  // A fragment base: row = bm*128 + wr*64 + (lane&15), k-bytes (lane>>4)*32;
  // per i add i*16 rows; per kt add kt*128 bytes.
  const char* aW = (const char*)(qb +
      (size_t)(bm * BM + wr * 64 + (lane & 15)) * DD) + (lane >> 4) * 32;

  f32x4 acc[4][4] = {};

  auto stageB = [&](int d, int kt) {
    #pragma unroll
    for (int it = 0; it < 4; ++it) {
      int p = it * 256 + tid;
      int r = p >> 3, c = p & 7, cs = c ^ (r & 7);
      gload16(bG + (size_t)r * DD + kt * BK + cs * 16,
              lds + d * 16384 + p * 16);
    }
  };

  i32x4 alo[4], ahi[4], nlo[4], nhi[4];
  auto loadA = [&](int kt, i32x4 (&lo)[4], i32x4 (&hi)[4]) {
    #pragma unroll
    for (int i = 0; i < 4; ++i)
      aload32(aW + (size_t)i * 16 * DD + kt * BK, lo[i], hi[i]);
  };

  auto compute = [&](int d, const i32x4 (&lo)[4], const i32x4 (&hi)[4]) {
    const char* Bbuf = lds + d * 16384;
    const int g2 = 2 * (lane >> 4);
    i32x8 bb[4];
    #pragma unroll
    for (int i = 0; i < 4; ++i) {
      int rb = wc * 64 + i * 16 + (lane & 15);
      i32x4 blo = *(const i32x4*)(Bbuf + rb * 128 + ((g2 ^ (rb & 7)) * 16));
      i32x4 bhi = *(const i32x4*)(Bbuf + rb * 128 + (((g2 + 1) ^ (rb & 7)) * 16));
      bb[i] = __builtin_shufflevector(blo, bhi, 0, 1, 2, 3, 4, 5, 6, 7);
    }
    #pragma unroll
    for (int i = 0; i < 4; ++i) {
      i32x8 af = __builtin_shufflevector(lo[i], hi[i], 0, 1, 2, 3, 4, 5, 6, 7);
      #pragma unroll
      for (int j = 0; j < 4; ++j)
        acc[i][j] = __builtin_amdgcn_mfma_scale_f32_16x16x128_f8f6f4(
            af, bb[j], acc[i][j], 0 /*A=e4m3*/, 0 /*B=e4m3*/,
            0, 0x7F7F7F7F, 0, 0x7F7F7F7F /*unit e8m0 scales*/);
    }
  };

  // 2-phase pipeline, 2-unrolled for register ping-pong (static indexing).
  // A loads for tile t are issued one __syncthreads before their use; the
  // barrier's vmcnt(0) drain makes them architecturally ready.
  loadA(0, alo, ahi); stageB(0, 0);
  __syncthreads();
  #pragma unroll 1
  for (int t = 0; t < KT; t += 2) {
    if (t + 1 < KT) { loadA(t + 1, nlo, nhi); stageB(1, t + 1); }
    compute(0, alo, ahi);
    __syncthreads();
    if (t + 2 < KT) { loadA(t + 2, alo, ahi); stageB(0, t + 2); }
    compute(1, nlo, nhi);
    __syncthreads();
  }

  // ---- epilogue: scores -> LDS (rotated, scalar both ways; R1-proven
  // conflict-free), strip top-4 as packed keys ----
  float* sc = (float*)lds;
  #pragma unroll
  for (int i = 0; i < 4; ++i)
    #pragma unroll
    for (int j = 0; j < 4; ++j)
      #pragma unroll
      for (int q = 0; q < 4; ++q) {
        int r = wr * 64 + i * 16 + (lane >> 4) * 4 + q;
        int c = wc * 64 + j * 16 + (lane & 15);
        sc[r * 128 + ((c + r) & 127)] = acc[i][j][q];
      }
  __syncthreads();

  // 256 threads = 128 rows x 2 strips of 64 cols. Branchless sorted-insert
  // of packed keys (17-bit ordered score | 15-bit global m-index).
  const int srow = tid >> 1, strip = tid & 1;
  unsigned k0 = 0, k1 = 0, k2 = 0, k3 = 0;
  for (int i = 0; i < 64; ++i) {
    int c = strip * 64 + i;
    float s = sc[srow * 128 + ((c + srow) & 127)];
    unsigned key = (ordf(s) & 0xFFFF8000u) | (unsigned)(bn * BN + c);
    unsigned b = key, t2;
    t2 = k0 < b ? k0 : b; k0 = k0 < b ? b : k0; b = t2;
    t2 = k1 < b ? k1 : b; k1 = k1 < b ? b : k1; b = t2;
    t2 = k2 < b ? k2 : b; k2 = k2 < b ? b : k2; b = t2;
    k3 = k3 < b ? b : k3;
  }
  unsigned* dst = cand_k + (size_t)(bm * BM + srow) * (NBN * 8) + bn * 8 + strip * 4;
  *(uint4*)dst = make_uint4(k0, k1, k2, k3);
}

// One wave per query row: top-16 of 2048 packed keys, exact fp32 rescore,
// stable top-4, gather synth rows and average.
__global__ __launch_bounds__(256) void finalize(
    const float* __restrict__ q, const float* __restrict__ m,
    const float* __restrict__ synth, const unsigned* __restrict__ cand_k,
    const float* __restrict__ inv_mn, float* __restrict__ out) {
  const int lane = threadIdx.x & 63;
  const int row  = blockIdx.x * 4 + (threadIdx.x >> 6);

  uint4 kk[8];
  const uint4* kp = (const uint4*)(cand_k + (size_t)row * (NBN * 8));
  #pragma unroll
  for (int ii = 0; ii < 8; ++ii) kk[ii] = kp[ii * 64 + lane];

  const float4* qp = (const float4*)(q + (size_t)row * DD);
  float4 qv[4];
  #pragma unroll
  for (int ph = 0; ph < 4; ++ph) qv[ph] = qp[ph * 64 + lane];

  unsigned wk[16];
  #pragma unroll
  for (int it = 0; it < 16; ++it) {
    unsigned lm = 0;
    #pragma unroll
    for (int ii = 0; ii < 8; ++ii) {
      unsigned a = kk[ii].x > kk[ii].y ? kk[ii].x : kk[ii].y;
      unsigned b = kk[ii].z > kk[ii].w ? kk[ii].z : kk[ii].w;
      a = a > b ? a : b;
      lm = lm > a ? lm : a;
    }
    #pragma unroll
    for (int o = 1; o < 64; o <<= 1) {
      unsigned other = (unsigned)__shfl_xor((int)lm, o, 64);
      lm = lm > other ? lm : other;
    }
    wk[it] = lm;
    #pragma unroll
    for (int ii = 0; ii < 8; ++ii) {
      kk[ii].x = kk[ii].x == lm ? 0u : kk[ii].x;
      kk[ii].y = kk[ii].y == lm ? 0u : kk[ii].y;
      kk[ii].z = kk[ii].z == lm ? 0u : kk[ii].z;
      kk[ii].w = kk[ii].w == lm ? 0u : kk[ii].w;
    }
  }

  float cosv[16]; int gidx[16];
  #pragma unroll
  for (int it = 0; it < 16; ++it) {
    int g = (int)(wk[it] & 0x7FFFu);
    gidx[it] = g;
    const float4* mp = (const float4*)(m + (size_t)g * DD);
    float d = 0.f;
    #pragma unroll
    for (int ph = 0; ph < 4; ++ph) {
      float4 mv = mp[ph * 64 + lane];
      d += mv.x * qv[ph].x + mv.y * qv[ph].y + mv.z * qv[ph].z + mv.w * qv[ph].w;
    }
    #pragma unroll
    for (int o = 1; o < 64; o <<= 1) d += __shfl_xor(d, o, 64);
    cosv[it] = d * inv_mn[g];
  }

  int sel[4]; bool used[16] = {};
  #pragma unroll
  for (int s = 0; s < 4; ++s) {
    float bv = -1e30f; int bg = 0x7FFFFFFF; int bj = -1;
    #pragma unroll
    for (int j = 0; j < 16; ++j) {
      bool better = !used[j] && (cosv[j] > bv || (cosv[j] == bv && gidx[j] < bg));
      bv = better ? cosv[j] : bv;
      bg = better ? gidx[j] : bg;
      bj = better ? j : bj;
    }
    sel[s] = bg;
    #pragma unroll
    for (int j = 0; j < 16; ++j) used[j] = used[j] || (j == bj);
  }

  const float4* s0 = (const float4*)(synth + (size_t)sel[0] * DD);
  const float4* s1 = (const float4*)(synth + (size_t)sel[1] * DD);
  const float4* s2 = (const float4*)(synth + (size_t)sel[2] * DD);
  const float4* s3 = (const float4*)(synth + (size_t)sel[3] * DD);
  float4* op = (float4*)(out + (size_t)row * DD);
  #pragma unroll
  for (int ph = 0; ph < 4; ++ph) {
    int ix = ph * 64 + lane;
    float4 a = s0[ix], b = s1[ix], c = s2[ix], d = s3[ix];
    float4 r;
    r.x = (a.x + b.x + c.x + d.x) * 0.25f;
    r.y = (a.y + b.y + c.y + d.y) * 0.25f;
    r.z = (a.z + b.z + c.z + d.z) * 0.25f;
    r.w = (a.w + b.w + c.w + d.w) * 0.25f;
    op[ix] = r;
  }
}

extern "C" void kernel_launch(void* const* d_in, const int* in_sizes, int n_in,
                              void* d_out, int out_size, void* d_ws, size_t ws_size,
                              hipStream_t stream) {
  (void)in_sizes; (void)n_in; (void)out_size; (void)ws_size;
  const float* q = (const float*)d_in[0];
  const float* m = (const float*)d_in[1];
  const float* s = (const float*)d_in[2];
  float* out = (float*)d_out;

  // ws layout: qb 2MB | mb 32MB (at 2MB) | inv_mn (at 40MB) | cand_k (at 41MB, 16MB)
  char* w = (char*)d_ws;
  unsigned char* qb     = (unsigned char*)w;
  unsigned char* mb     = (unsigned char*)(w + (2ull << 20));
  float*         inv_mn = (float*)(w + (40ull << 20));
  unsigned*      cand_k = (unsigned*)(w + (41ull << 20));

  nrmcvt8<<<N1, 256, 0, stream>>>(q, qb, nullptr);
  nrmcvt8<<<N2, 256, 0, stream>>>(m, mb, inv_mn);
  gemm_topk<<<NBM * NBN, 256, 0, stream>>>(qb, mb, cand_k);
  finalize<<<N1 / 4, 256, 0, stream>>>(q, m, s, cand_k, inv_mn, out);
}

// Round 8
// 181.303 us; speedup vs baseline: 1.3674x; 1.2713x over previous
//
#include <hip/hip_runtime.h>

#define N1 2048
#define N2 32768
#define DD 1024
#define BM 128
#define BN 128
#define BK 128          // fp8 elements per K-tile = 128 B/row
#define NBN (N2 / BN)   // 256
#define NBM (N1 / BM)   // 16
#define KT  (DD / BK)   // 8

typedef __attribute__((ext_vector_type(8))) int   i32x8;
typedef __attribute__((ext_vector_type(4))) int   i32x4;
typedef __attribute__((ext_vector_type(4))) float f32x4;

typedef const __attribute__((address_space(1))) void gv_t;
typedef __attribute__((address_space(3))) void       lv_t;

__device__ __forceinline__ void gload16(const void* g, void* l) {
  __builtin_amdgcn_global_load_lds((gv_t*)g, (lv_t*)l, 16, 0, 0);
}

__device__ __forceinline__ unsigned ordf(float x) {  // order-preserving f32->u32
  union { float f; unsigned u; } a; a.f = x;
  return a.u ^ ((unsigned)((int)a.u >> 31) | 0x80000000u);
}

// Row-normalize + convert to fp8 e4m3 (x16 pre-scale; ranking is
// scale-invariant, final rescore is exact fp32).
__global__ __launch_bounds__(256) void nrmcvt8(const float* __restrict__ src,
                                               unsigned char* __restrict__ dst,
                                               float* __restrict__ invn) {
  const int row = blockIdx.x, t = threadIdx.x;
  const float4* s4 = (const float4*)(src + (size_t)row * DD);
  float4 v = s4[t];
  float ss = v.x * v.x + v.y * v.y + v.z * v.z + v.w * v.w;
  #pragma unroll
  for (int o = 32; o > 0; o >>= 1) ss += __shfl_down(ss, o, 64);
  __shared__ float red[4];
  if ((t & 63) == 0) red[t >> 6] = ss;
  __syncthreads();
  float inv = 1.0f / sqrtf(red[0] + red[1] + red[2] + red[3]);
  float sc = inv * 16.0f;
  int p = 0;
  p = __builtin_amdgcn_cvt_pk_fp8_f32(v.x * sc, v.y * sc, p, false);
  p = __builtin_amdgcn_cvt_pk_fp8_f32(v.z * sc, v.w * sc, p, true);
  ((unsigned*)(dst + (size_t)row * DD))[t] = (unsigned)p;
  if (invn != nullptr && t == 0) invn[row] = inv;
}

// MX-fp8 (unit-scale) MFMA GEMM + fused per-row/per-64col-strip top-4,
// packed as (17-bit ordered score | 15-bit global m-index) keys.
// R4 structure (proven 119us) + startup stagger: co-resident blocks are
// offset ~0-1000cy so one block's LDS-read phase overlaps the other's
// MFMA phase (anti-phase pipelining of the two CU-shared pipes).
__global__ __launch_bounds__(256, 2) void gemm_topk(
    const unsigned char* __restrict__ qb,
    const unsigned char* __restrict__ mbn,
    unsigned* __restrict__ cand_k) {
  __shared__ char lds[65536];  // dbuf staging (2 x (16KB A + 16KB B)) / scores union
  const int tid  = threadIdx.x;
  const int lane = tid & 63;
  const int w = tid >> 6, wr = w >> 1, wc = w & 1;

  // XCD-aware bijective swizzle (grid 4096 % 8 == 0)
  int bid = blockIdx.x;
  int swz = (bid & 7) * (NBM * NBN / 8) + (bid >> 3);
  const int bm = swz >> 8;          // NBN == 256
  const int bn = swz & (NBN - 1);

  // Startup stagger: pseudo-random 0..15 x ~64cy per block; whatever pair of
  // blocks lands on a CU, they likely start ~half-a-kt apart -> anti-phase.
  {
    int amt = (bid * 37) & 15;
    for (int k = 0; k < amt; ++k) __builtin_amdgcn_s_sleep(1);
  }

  const char* aG = (const char*)(qb  + (size_t)bm * BM * DD);
  const char* bG = (const char*)(mbn + (size_t)bn * BN * DD);

  f32x4 acc[4][4] = {};

  // Stage A/B tile kt into buffer d. Linear LDS dest via global_load_lds;
  // XOR swizzle (chunk ^= row&7) applied on the GLOBAL source (rule #21).
  auto stage = [&](int d, int kt) {
    #pragma unroll
    for (int it = 0; it < 4; ++it) {
      int p = it * 256 + tid;
      int r = p >> 3, c = p & 7, cs = c ^ (r & 7);
      gload16(aG + (size_t)r * DD + kt * BK + cs * 16,
              lds + d * 32768 + p * 16);
    }
    #pragma unroll
    for (int it = 0; it < 4; ++it) {
      int p = it * 256 + tid;
      int r = p >> 3, c = p & 7, cs = c ^ (r & 7);
      gload16(bG + (size_t)r * DD + kt * BK + cs * 16,
              lds + d * 32768 + 16384 + p * 16);
    }
  };

  auto compute = [&](int d) {
    const char* Abuf = lds + d * 32768;
    const char* Bbuf = Abuf + 16384;
    // fragment: lane holds row (l&15)+16*i, k-bytes [(l>>4)*32, +32)
    // = swizzled chunks (2g)^(r&7), (2g+1)^(r&7)
    const int g2 = 2 * (lane >> 4);
    i32x8 af[4], bb[4];
    #pragma unroll
    for (int i = 0; i < 4; ++i) {
      int ra = wr * 64 + i * 16 + (lane & 15);
      i32x4 lo = *(const i32x4*)(Abuf + ra * 128 + ((g2 ^ (ra & 7)) * 16));
      i32x4 hi = *(const i32x4*)(Abuf + ra * 128 + (((g2 + 1) ^ (ra & 7)) * 16));
      af[i] = __builtin_shufflevector(lo, hi, 0, 1, 2, 3, 4, 5, 6, 7);
      int rb = wc * 64 + i * 16 + (lane & 15);
      i32x4 blo = *(const i32x4*)(Bbuf + rb * 128 + ((g2 ^ (rb & 7)) * 16));
      i32x4 bhi = *(const i32x4*)(Bbuf + rb * 128 + (((g2 + 1) ^ (rb & 7)) * 16));
      bb[i] = __builtin_shufflevector(blo, bhi, 0, 1, 2, 3, 4, 5, 6, 7);
    }
    #pragma unroll
    for (int i = 0; i < 4; ++i)
      #pragma unroll
      for (int j = 0; j < 4; ++j)
        acc[i][j] = __builtin_amdgcn_mfma_scale_f32_16x16x128_f8f6f4(
            af[i], bb[j], acc[i][j], 0 /*A=e4m3*/, 0 /*B=e4m3*/,
            0, 0x7F7F7F7F, 0, 0x7F7F7F7F /*unit e8m0 scales*/);
  };

  // 2-phase pipeline (R4-proven): issue next-tile loads, compute current,
  // one full drain + barrier per tile (__syncthreads).
  stage(0, 0);
  __syncthreads();
  #pragma unroll 1
  for (int t = 0; t < KT; ++t) {
    if (t + 1 < KT) stage((t + 1) & 1, t + 1);
    compute(t & 1);
    __syncthreads();
  }

  // ---- epilogue: scores -> LDS (rotated, conflict-free), strip top-4 ----
  float* sc = (float*)lds;
  #pragma unroll
  for (int i = 0; i < 4; ++i)
    #pragma unroll
    for (int j = 0; j < 4; ++j)
      #pragma unroll
      for (int q = 0; q < 4; ++q) {
        int r = wr * 64 + i * 16 + (lane >> 4) * 4 + q;
        int c = wc * 64 + j * 16 + (lane & 15);
        sc[r * 128 + ((c + r) & 127)] = acc[i][j][q];
      }
  __syncthreads();

  // 256 threads = 128 rows x 2 strips of 64 cols. Branchless sorted-insert
  // of packed keys (17-bit ordered score | 15-bit global m-index).
  const int srow = tid >> 1, strip = tid & 1;
  unsigned k0 = 0, k1 = 0, k2 = 0, k3 = 0;
  for (int i = 0; i < 64; ++i) {
    int c = strip * 64 + i;
    float s = sc[srow * 128 + ((c + srow) & 127)];
    unsigned key = (ordf(s) & 0xFFFF8000u) | (unsigned)(bn * BN + c);
    unsigned b = key, t2;
    t2 = k0 < b ? k0 : b; k0 = k0 < b ? b : k0; b = t2;
    t2 = k1 < b ? k1 : b; k1 = k1 < b ? b : k1; b = t2;
    t2 = k2 < b ? k2 : b; k2 = k2 < b ? b : k2; b = t2;
    k3 = k3 < b ? b : k3;
  }
  unsigned* dst = cand_k + (size_t)(bm * BM + srow) * (NBN * 8) + bn * 8 + strip * 4;
  *(uint4*)dst = make_uint4(k0, k1, k2, k3);
}

// One wave per query row: top-16 of 2048 packed keys, exact fp32 rescore,
// stable top-4, gather synth rows and average.
__global__ __launch_bounds__(256) void finalize(
    const float* __restrict__ q, const float* __restrict__ m,
    const float* __restrict__ synth, const unsigned* __restrict__ cand_k,
    const float* __restrict__ inv_mn, float* __restrict__ out) {
  const int lane = threadIdx.x & 63;
  const int row  = blockIdx.x * 4 + (threadIdx.x >> 6);

  uint4 kk[8];
  const uint4* kp = (const uint4*)(cand_k + (size_t)row * (NBN * 8));
  #pragma unroll
  for (int ii = 0; ii < 8; ++ii) kk[ii] = kp[ii * 64 + lane];

  const float4* qp = (const float4*)(q + (size_t)row * DD);
  float4 qv[4];
  #pragma unroll
  for (int ph = 0; ph < 4; ++ph) qv[ph] = qp[ph * 64 + lane];

  unsigned wk[16];
  #pragma unroll
  for (int it = 0; it < 16; ++it) {
    unsigned lm = 0;
    #pragma unroll
    for (int ii = 0; ii < 8; ++ii) {
      unsigned a = kk[ii].x > kk[ii].y ? kk[ii].x : kk[ii].y;
      unsigned b = kk[ii].z > kk[ii].w ? kk[ii].z : kk[ii].w;
      a = a > b ? a : b;
      lm = lm > a ? lm : a;
    }
    #pragma unroll
    for (int o = 1; o < 64; o <<= 1) {
      unsigned other = (unsigned)__shfl_xor((int)lm, o, 64);
      lm = lm > other ? lm : other;
    }
    wk[it] = lm;
    #pragma unroll
    for (int ii = 0; ii < 8; ++ii) {
      kk[ii].x = kk[ii].x == lm ? 0u : kk[ii].x;
      kk[ii].y = kk[ii].y == lm ? 0u : kk[ii].y;
      kk[ii].z = kk[ii].z == lm ? 0u : kk[ii].z;
      kk[ii].w = kk[ii].w == lm ? 0u : kk[ii].w;
    }
  }

  float cosv[16]; int gidx[16];
  #pragma unroll
  for (int it = 0; it < 16; ++it) {
    int g = (int)(wk[it] & 0x7FFFu);
    gidx[it] = g;
    const float4* mp = (const float4*)(m + (size_t)g * DD);
    float d = 0.f;
    #pragma unroll
    for (int ph = 0; ph < 4; ++ph) {
      float4 mv = mp[ph * 64 + lane];
      d += mv.x * qv[ph].x + mv.y * qv[ph].y + mv.z * qv[ph].z + mv.w * qv[ph].w;
    }
    #pragma unroll
    for (int o = 1; o < 64; o <<= 1) d += __shfl_xor(d, o, 64);
    cosv[it] = d * inv_mn[g];
  }

  int sel[4]; bool used[16] = {};
  #pragma unroll
  for (int s = 0; s < 4; ++s) {
    float bv = -1e30f; int bg = 0x7FFFFFFF; int bj = -1;
    #pragma unroll
    for (int j = 0; j < 16; ++j) {
      bool better = !used[j] && (cosv[j] > bv || (cosv[j] == bv && gidx[j] < bg));
      bv = better ? cosv[j] : bv;
      bg = better ? gidx[j] : bg;
      bj = better ? j : bj;
    }
    sel[s] = bg;
    #pragma unroll
    for (int j = 0; j < 16; ++j) used[j] = used[j] || (j == bj);
  }

  const float4* s0 = (const float4*)(synth + (size_t)sel[0] * DD);
  const float4* s1 = (const float4*)(synth + (size_t)sel[1] * DD);
  const float4* s2 = (const float4*)(synth + (size_t)sel[2] * DD);
  const float4* s3 = (const float4*)(synth + (size_t)sel[3] * DD);
  float4* op = (float4*)(out + (size_t)row * DD);
  #pragma unroll
  for (int ph = 0; ph < 4; ++ph) {
    int ix = ph * 64 + lane;
    float4 a = s0[ix], b = s1[ix], c = s2[ix], d = s3[ix];
    float4 r;
    r.x = (a.x + b.x + c.x + d.x) * 0.25f;
    r.y = (a.y + b.y + c.y + d.y) * 0.25f;
    r.z = (a.z + b.z + c.z + d.z) * 0.25f;
    r.w = (a.w + b.w + c.w + d.w) * 0.25f;
    op[ix] = r;
  }
}

extern "C" void kernel_launch(void* const* d_in, const int* in_sizes, int n_in,
                              void* d_out, int out_size, void* d_ws, size_t ws_size,
                              hipStream_t stream) {
  (void)in_sizes; (void)n_in; (void)out_size; (void)ws_size;
  const float* q = (const float*)d_in[0];
  const float* m = (const float*)d_in[1];
  const float* s = (const float*)d_in[2];
  float* out = (float*)d_out;

  // ws layout: qb 2MB | mb 32MB (at 2MB) | inv_mn (at 40MB) | cand_k (at 41MB, 16MB)
  char* w = (char*)d_ws;
  unsigned char* qb     = (unsigned char*)w;
  unsigned char* mb     = (unsigned char*)(w + (2ull << 20));
  float*         inv_mn = (float*)(w + (40ull << 20));
  unsigned*      cand_k = (unsigned*)(w + (41ull << 20));

  nrmcvt8<<<N1, 256, 0, stream>>>(q, qb, nullptr);
  nrmcvt8<<<N2, 256, 0, stream>>>(m, mb, inv_mn);
  gemm_topk<<<NBM * NBN, 256, 0, stream>>>(qb, mb, cand_k);
  finalize<<<N1 / 4, 256, 0, stream>>>(q, m, s, cand_k, inv_mn, out);
}